// Round 10
// baseline (1932.327 us; speedup 1.0000x reference)
//
#include <hip/hip_runtime.h>
#include <math.h>

constexpr int B  = 4;
constexpr int S  = 12;
constexpr int N  = 20000;
constexpr int HD = 64;
constexpr int E0 = 640000;
constexpr int EL = E0 + N;      // edges + self loops
constexpr int BN = B * N;
constexpr int CAP = 128;        // padded CSR bucket capacity (deg: mean 32, sd 5.7)

// ---------------- padded-bucket CSR build: one kernel, no scan ---------------
__global__ void scatter_kernel(const int* __restrict__ ei, int* __restrict__ cnt,
                               int* __restrict__ perm) {
    int e = blockIdx.x * blockDim.x + threadIdx.x;
    if (e >= EL) return;
    int s, d;
    if (e < E0) { s = ei[e]; d = ei[E0 + e]; }
    else        { s = e - E0; d = s; }
    int pos = atomicAdd(&cnt[d], 1) & (CAP - 1);   // mask: can't corrupt neighbors
    perm[d * CAP + pos] = s;
}

// ---- conv weight transpose: cwD[dt*4096 + c*64 + o] = cw[o*192 + c*3 + dt] --
__global__ void tw_kernel(const float* __restrict__ cw, float* __restrict__ cwD) {
    int i = blockIdx.x * blockDim.x + threadIdx.x;
    if (i >= HD * HD * 3) return;
    int o = i / (HD * 3), rem = i % (HD * 3), c = rem / 3, dt = rem % 3;
    cwD[dt * (HD * HD) + c * HD + o] = cw[i];
}

// ======== gemm family v3: lane = k, weights resident in VGPRs ===============
// wave processes 16 nodes; node rows broadcast from LDS (wave-uniform addr);
// xe stored directly (coalesced 256B per node); es/ed via butterfly shuffle.
constexpr int GT = 64;                  // nodes per block (4 waves x 16)

template<int H>
__global__ __launch_bounds__(256, 4)
void gemm_attn_kernel(const float* __restrict__ hin, const float* __restrict__ w,
                      const float* __restrict__ asrc, const float* __restrict__ adst,
                      float* __restrict__ xe, float* __restrict__ es, float* __restrict__ ed) {
    __shared__ float tile[GT * HD];
    int base = blockIdx.x * GT;
    for (int i = threadIdx.x; i < GT * (HD / 4); i += 256)
        ((float4*)tile)[i] = ((const float4*)(hin + (size_t)base * HD))[i];
    int lane = threadIdx.x & 63;
    float wres[HD];                     // w[c][lane], c compile-time -> VGPRs
    #pragma unroll
    for (int c = 0; c < HD; ++c) wres[c] = w[c * HD + lane];
    float as_ = asrc[lane], ad_ = adst[lane];
    __syncthreads();
    int wvid = threadIdx.x >> 6;
    for (int j = wvid * 16; j < wvid * 16 + 16; ++j) {
        int t = base + j;
        float acc = 0.f;
        #pragma unroll
        for (int cq = 0; cq < 16; ++cq) {
            float4 r = ((const float4*)tile)[j * 16 + cq];   // broadcast read
            acc = fmaf(r.x, wres[4 * cq + 0], acc);
            acc = fmaf(r.y, wres[4 * cq + 1], acc);
            acc = fmaf(r.z, wres[4 * cq + 2], acc);
            acc = fmaf(r.w, wres[4 * cq + 3], acc);
        }
        xe[(size_t)t * HD + lane] = acc;                     // coalesced
        float t0 = acc * as_, t1 = acc * ad_;
        if (H == 8) {
            #pragma unroll
            for (int m = 1; m < 8; m <<= 1) {
                t0 += __shfl_xor(t0, m, 64);
                t1 += __shfl_xor(t1, m, 64);
            }
            if ((lane & 7) == 0) {
                es[t * 8 + (lane >> 3)] = t0;
                ed[t * 8 + (lane >> 3)] = t1;
            }
        } else {
            #pragma unroll
            for (int m = 1; m < 64; m <<= 1) {
                t0 += __shfl_xor(t0, m, 64);
                t1 += __shfl_xor(t1, m, 64);
            }
            if (lane == 0) { es[t] = t0; ed[t] = t1; }
        }
    }
}

// layer 0: proj fused in. h row computed per-lane, broadcast via LDS row write.
__global__ __launch_bounds__(256, 4)
void fused0_kernel(const float* __restrict__ x, const float* __restrict__ pw,
                   const float* __restrict__ pb, const float* __restrict__ w,
                   const float* __restrict__ asrc, const float* __restrict__ adst,
                   float* __restrict__ xe, float* __restrict__ es, float* __restrict__ ed) {
    __shared__ float tile[GT * HD];
    __shared__ float xt[S * GT];
    int base = blockIdx.x * GT;
    for (int i = threadIdx.x; i < S * GT; i += 256) {
        int s = i >> 6, nl = i & 63;
        int t = base + nl, bb = t / N, n = t - bb * N;
        xt[i] = x[(bb * S + s) * N + n];          // coalesced per s-segment
    }
    int lane = threadIdx.x & 63;
    float wres[HD];
    #pragma unroll
    for (int c = 0; c < HD; ++c) wres[c] = w[c * HD + lane];
    float pwres[S];
    #pragma unroll
    for (int s = 0; s < S; ++s) pwres[s] = pw[s * HD + lane];
    float pbv = pb[lane];
    float as_ = asrc[lane], ad_ = adst[lane];
    __syncthreads();
    int wvid = threadIdx.x >> 6;
    // phase A: this wave's 16 h-rows (lane = channel), written to tile
    for (int j = wvid * 16; j < wvid * 16 + 16; ++j) {
        float hl = pbv;
        #pragma unroll
        for (int s = 0; s < S; ++s)
            hl = fmaf(xt[s * GT + j], pwres[s], hl);         // broadcast read
        tile[j * HD + lane] = hl;                            // own wave's row
    }
    // phase B: gemm + attn (reads only this wave's rows -> no barrier needed)
    for (int j = wvid * 16; j < wvid * 16 + 16; ++j) {
        int t = base + j;
        float acc = 0.f;
        #pragma unroll
        for (int cq = 0; cq < 16; ++cq) {
            float4 r = ((const float4*)tile)[j * 16 + cq];
            acc = fmaf(r.x, wres[4 * cq + 0], acc);
            acc = fmaf(r.y, wres[4 * cq + 1], acc);
            acc = fmaf(r.z, wres[4 * cq + 2], acc);
            acc = fmaf(r.w, wres[4 * cq + 3], acc);
        }
        xe[(size_t)t * HD + lane] = acc;
        float t0 = acc * as_, t1 = acc * ad_;
        #pragma unroll
        for (int m = 1; m < 8; m <<= 1) {
            t0 += __shfl_xor(t0, m, 64);
            t1 += __shfl_xor(t1, m, 64);
        }
        if ((lane & 7) == 0) {
            es[t * 8 + (lane >> 3)] = t0;
            ed[t * 8 + (lane >> 3)] = t1;
        }
    }
}

// ------- fused aggregation: one wave per (batch,node) ------------------------
// 4 groups x 16 lanes; group owns an edge, lane owns 4 channels (float4).
// XCD swizzle: batch bb's blocks land on XCDs {2bb,2bb+1} (round-robin CP
// assumption) so bb's 5.1MB xe slice stays L2-resident. Heuristic only.
template<int H, bool DO_ELU>
__global__ __launch_bounds__(256, 8)
void agg_kernel(const float* __restrict__ xe, const float* __restrict__ es,
                const float* __restrict__ ed, const int* __restrict__ cnt,
                const int* __restrict__ perm, const float* __restrict__ bias,
                float* __restrict__ hout) {
    int g = blockIdx.x;                       // 20000 blocks, multiple of 8
    int bb   = (g & 7) >> 1;                  // batch from XCD pair
    int idx  = (g >> 3) * 2 + (g & 1);        // 0..4999 within batch
    int node = idx * 4 + (threadIdx.x >> 6);  // < 20000
    int lane  = threadIdx.x & 63;
    int group = lane >> 4;
    int c4    = lane & 15;
    int deg = cnt[node];
    int baseE = node * CAP;
    int h = (H == 8) ? (c4 >> 1) : 0;        // channels 4*c4..+3 lie in one head
    const float*  es_b = es + bb * (N * H);
    const float4* xe4  = (const float4*)(xe + bb * (N * HD));
    float edv = ed[(bb * N + node) * H + h];
    float4 acc = {0.f, 0.f, 0.f, 0.f};
    float ssum = 0.f;
    #pragma unroll 4
    for (int jb = 0; jb < deg; jb += 4) {
        int j = jb + group;
        bool valid = (j < deg);
        int src = perm[baseE + (valid ? j : 0)];     // slot 0 always exists
        float e = es_b[src * H + h] + edv;
        e = fmaxf(e, 0.2f * e);                      // leaky_relu(0.2)
        float p = valid ? __expf(e) : 0.f;
        ssum += p;
        float4 xv = xe4[src * 16 + c4];              // 256B/group gather
        acc.x = fmaf(p, xv.x, acc.x);
        acc.y = fmaf(p, xv.y, acc.y);
        acc.z = fmaf(p, xv.z, acc.z);
        acc.w = fmaf(p, xv.w, acc.w);
    }
    #pragma unroll
    for (int m = 16; m < 64; m <<= 1) {
        acc.x += __shfl_xor(acc.x, m, 64);
        acc.y += __shfl_xor(acc.y, m, 64);
        acc.z += __shfl_xor(acc.z, m, 64);
        acc.w += __shfl_xor(acc.w, m, 64);
        ssum  += __shfl_xor(ssum,  m, 64);
    }
    if (lane < 16) {
        float inv = 1.f / ssum;
        const float4* b4 = (const float4*)bias;
        float4 bv = b4[c4];
        float4 r;
        r.x = acc.x * inv + bv.x;
        r.y = acc.y * inv + bv.y;
        r.z = acc.z * inv + bv.z;
        r.w = acc.w * inv + bv.w;
        if (DO_ELU) {
            r.x = (r.x > 0.f) ? r.x : expm1f(r.x);
            r.y = (r.y > 0.f) ? r.y : expm1f(r.y);
            r.z = (r.z > 0.f) ? r.z : expm1f(r.z);
            r.w = (r.w > 0.f) ? r.w : expm1f(r.w);
        }
        ((float4*)hout)[(bb * N + node) * 16 + c4] = r;
    }
}

// ======== conv v6: two-pass fused-dt, register acc, no part[] LDS ===========
// lane = out-channel o. Pass A: w0,w1 resident; each tile row read ONCE,
// contributing dt=0 to acc[r] and dt=1 to acc[r-1]. Pass B: w2, rows read
// once more for dt=2. 528 broadcast reads/wave vs 768 in v5; acc[16] in
// registers (compile-time indexed, full unroll). Peak live ~190 VGPR < 256
// cap at LB(256,2) -> no spill (watch FETCH/WRITE for the spill signature).
constexpr int CN = 64;                  // nodes per block (4 waves x 16)
__global__ __launch_bounds__(256, 2)
void conv_out_kernel(const float* __restrict__ h, const float* __restrict__ cwD,
                     const float* __restrict__ cb, const float* __restrict__ ow,
                     const float* __restrict__ ob, float* __restrict__ out) {
    __shared__ float tile[(CN + 2) * HD];        // rows base-1 .. base+CN (16.9KB)
    int bb = blockIdx.y;
    int base = blockIdx.x * CN;
    for (int i = threadIdx.x; i < (CN + 2) * (HD / 4); i += 256) {
        int row = i >> 4, q = i & 15;
        int m = base - 1 + row;
        float4 v = {0.f, 0.f, 0.f, 0.f};
        if (m >= 0 && m < N) v = ((const float4*)(h + ((size_t)bb * N + m) * HD))[q];
        ((float4*)tile)[i] = v;
    }
    int lane = threadIdx.x & 63;        // = output channel o
    int wvid = threadIdx.x >> 6;
    int nb = wvid * 16;                 // this wave's local node start
    float cbv = cb[lane];
    float ow0 = ow[lane * 3 + 0], ow1 = ow[lane * 3 + 1], ow2 = ow[lane * 3 + 2];
    float ob0 = ob[0], ob1 = ob[1], ob2 = ob[2];
    float acc[16];
    #pragma unroll
    for (int j = 0; j < 16; ++j) acc[j] = cbv;
    // pass A weights (coalesced lane-indexed loads, overlap with staging)
    float w0[HD], w1[HD];
    #pragma unroll
    for (int c = 0; c < HD; ++c) w0[c] = cwD[c * HD + lane];
    #pragma unroll
    for (int c = 0; c < HD; ++c) w1[c] = cwD[HD * HD + c * HD + lane];
    __syncthreads();
    // pass A: rows nb+0 .. nb+16, each read once -> dt0 into acc[r], dt1 into acc[r-1]
    #pragma unroll
    for (int r = 0; r <= 16; ++r) {
        const float4* rp = (const float4*)(tile + (nb + r) * HD);
        float a0 = 0.f, a1 = 0.f;
        #pragma unroll
        for (int cq = 0; cq < 16; ++cq) {
            float4 rv = rp[cq];                  // broadcast read (uniform addr)
            a0 = fmaf(rv.x, w0[4 * cq + 0], a0);
            a0 = fmaf(rv.y, w0[4 * cq + 1], a0);
            a0 = fmaf(rv.z, w0[4 * cq + 2], a0);
            a0 = fmaf(rv.w, w0[4 * cq + 3], a0);
            a1 = fmaf(rv.x, w1[4 * cq + 0], a1);
            a1 = fmaf(rv.y, w1[4 * cq + 1], a1);
            a1 = fmaf(rv.z, w1[4 * cq + 2], a1);
            a1 = fmaf(rv.w, w1[4 * cq + 3], a1);
        }
        if (r <= 15) acc[r] += a0;
        if (r >= 1)  acc[r - 1] += a1;
    }
    // pass B: dt=2 -> acc[r-2]
    float w2[HD];
    #pragma unroll
    for (int c = 0; c < HD; ++c) w2[c] = cwD[2 * HD * HD + c * HD + lane];
    #pragma unroll
    for (int r = 2; r <= 17; ++r) {
        const float4* rp = (const float4*)(tile + (nb + r) * HD);
        float a2 = 0.f;
        #pragma unroll
        for (int cq = 0; cq < 16; ++cq) {
            float4 rv = rp[cq];
            a2 = fmaf(rv.x, w2[4 * cq + 0], a2);
            a2 = fmaf(rv.y, w2[4 * cq + 1], a2);
            a2 = fmaf(rv.z, w2[4 * cq + 2], a2);
            a2 = fmaf(rv.w, w2[4 * cq + 3], a2);
        }
        acc[r - 2] += a2;
    }
    // epilogue: relu + 64->3 via butterfly
    #pragma unroll
    for (int j = 0; j < 16; ++j) {
        float v = fmaxf(acc[j], 0.f);
        float t0 = v * ow0, t1 = v * ow1, t2 = v * ow2;
        #pragma unroll
        for (int m = 1; m < 64; m <<= 1) {
            t0 += __shfl_xor(t0, m, 64);
            t1 += __shfl_xor(t1, m, 64);
            t2 += __shfl_xor(t2, m, 64);
        }
        int n = base + nb + j;
        if (lane < 3 && n < N) {
            float r = (lane == 0) ? t0 + ob0 : (lane == 1) ? t1 + ob1 : t2 + ob2;
            out[(size_t)bb * 3 * N + lane * N + n] = r;
        }
    }
}

extern "C" void kernel_launch(void* const* d_in, const int* in_sizes, int n_in,
                              void* d_out, int out_size, void* d_ws, size_t ws_size,
                              hipStream_t stream) {
    const float* x      = (const float*)d_in[0];
    const int*   ei     = (const int*)  d_in[1];
    const float* proj_w = (const float*)d_in[2];
    const float* proj_b = (const float*)d_in[3];
    const float* g_w [3] = {(const float*)d_in[4], (const float*)d_in[8],  (const float*)d_in[12]};
    const float* g_as[3] = {(const float*)d_in[5], (const float*)d_in[9],  (const float*)d_in[13]};
    const float* g_ad[3] = {(const float*)d_in[6], (const float*)d_in[10], (const float*)d_in[14]};
    const float* g_b [3] = {(const float*)d_in[7], (const float*)d_in[11], (const float*)d_in[15]};
    const float* conv_w = (const float*)d_in[16];
    const float* conv_b = (const float*)d_in[17];
    const float* out_w  = (const float*)d_in[18];
    const float* out_b  = (const float*)d_in[19];
    float* out = (float*)d_out;

    // workspace layout (fp32 elements)
    float* bufA = (float*)d_ws;                      // BN*HD
    float* bufX = bufA + (size_t)BN * HD;            // BN*HD
    float* es   = bufX + (size_t)BN * HD;            // BN*8 (max H)
    float* ed   = es   + (size_t)BN * 8;             // BN*8
    int* cnt  = (int*)(ed + (size_t)BN * 8);         // N
    int* perm = cnt + N;                             // N*CAP
    float* cwD = (float*)(perm + (size_t)N * CAP);   // 3*64*64

    const int TB = 256;
    const int gE = (EL + TB - 1) / TB;

    // CSR build: memset + single scatter (padded buckets, no scan)
    hipMemsetAsync(cnt, 0, N * sizeof(int), stream);
    scatter_kernel<<<gE, TB, 0, stream>>>(ei, cnt, perm);

    // conv weight transpose to [dt][c][o]
    tw_kernel<<<(HD * HD * 3 + TB - 1) / TB, TB, 0, stream>>>(conv_w, cwD);

    // layer 0: proj + gemm + attn fused (reads x directly)
    fused0_kernel<<<BN / GT, TB, 0, stream>>>(x, proj_w, proj_b, g_w[0], g_as[0], g_ad[0],
                                              bufX, es, ed);
    agg_kernel<8, true><<<BN / 4, TB, 0, stream>>>(bufX, es, ed, cnt, perm, g_b[0], bufA);

    // layer 1 (H=8) + ELU
    gemm_attn_kernel<8><<<BN / GT, TB, 0, stream>>>(bufA, g_w[1], g_as[1], g_ad[1], bufX, es, ed);
    agg_kernel<8, true><<<BN / 4, TB, 0, stream>>>(bufX, es, ed, cnt, perm, g_b[1], bufA);

    // layer 2 (H=1), no ELU
    gemm_attn_kernel<1><<<BN / GT, TB, 0, stream>>>(bufA, g_w[2], g_as[2], g_ad[2], bufX, es, ed);
    agg_kernel<1, false><<<BN / 4, TB, 0, stream>>>(bufX, es, ed, cnt, perm, g_b[2], bufA);

    // conv1d(k=3) + relu + final projection, writes [B,3,N]
    conv_out_kernel<<<dim3((N + CN - 1) / CN, B), TB, 0, stream>>>(bufA, cwD, conv_b, out_w, out_b, out);
}

// Round 11
// 730.419 us; speedup vs baseline: 2.6455x; 2.6455x over previous
//
#include <hip/hip_runtime.h>
#include <math.h>

constexpr int B  = 4;
constexpr int S  = 12;
constexpr int N  = 20000;
constexpr int HD = 64;
constexpr int E0 = 640000;
constexpr int EL = E0 + N;      // edges + self loops
constexpr int BN = B * N;
constexpr int CAP = 128;        // padded CSR bucket capacity (deg: mean 32, sd 5.7)

// ---------------- padded-bucket CSR build: one kernel, no scan ---------------
__global__ void scatter_kernel(const int* __restrict__ ei, int* __restrict__ cnt,
                               int* __restrict__ perm) {
    int e = blockIdx.x * blockDim.x + threadIdx.x;
    if (e >= EL) return;
    int s, d;
    if (e < E0) { s = ei[e]; d = ei[E0 + e]; }
    else        { s = e - E0; d = s; }
    int pos = atomicAdd(&cnt[d], 1) & (CAP - 1);   // mask: can't corrupt neighbors
    perm[d * CAP + pos] = s;
}

// ---- conv weight transpose: cwD[dt*4096 + c*64 + o] = cw[o*192 + c*3 + dt] --
__global__ void tw_kernel(const float* __restrict__ cw, float* __restrict__ cwD) {
    int i = blockIdx.x * blockDim.x + threadIdx.x;
    if (i >= HD * HD * 3) return;
    int o = i / (HD * 3), rem = i % (HD * 3), c = rem / 3, dt = rem % 3;
    cwD[dt * (HD * HD) + c * HD + o] = cw[i];
}

// ======== gemm family v3: lane = k, weights resident in VGPRs ===============
// wave processes 16 nodes; node rows broadcast from LDS (wave-uniform addr);
// xe stored directly (coalesced 256B per node); es/ed via butterfly shuffle.
constexpr int GT = 64;                  // nodes per block (4 waves x 16)

template<int H>
__global__ __launch_bounds__(256, 4)
void gemm_attn_kernel(const float* __restrict__ hin, const float* __restrict__ w,
                      const float* __restrict__ asrc, const float* __restrict__ adst,
                      float* __restrict__ xe, float* __restrict__ es, float* __restrict__ ed) {
    __shared__ float tile[GT * HD];
    int base = blockIdx.x * GT;
    for (int i = threadIdx.x; i < GT * (HD / 4); i += 256)
        ((float4*)tile)[i] = ((const float4*)(hin + (size_t)base * HD))[i];
    int lane = threadIdx.x & 63;
    float wres[HD];                     // w[c][lane], c compile-time -> VGPRs
    #pragma unroll
    for (int c = 0; c < HD; ++c) wres[c] = w[c * HD + lane];
    float as_ = asrc[lane], ad_ = adst[lane];
    __syncthreads();
    int wvid = threadIdx.x >> 6;
    for (int j = wvid * 16; j < wvid * 16 + 16; ++j) {
        int t = base + j;
        float acc = 0.f;
        #pragma unroll
        for (int cq = 0; cq < 16; ++cq) {
            float4 r = ((const float4*)tile)[j * 16 + cq];   // broadcast read
            acc = fmaf(r.x, wres[4 * cq + 0], acc);
            acc = fmaf(r.y, wres[4 * cq + 1], acc);
            acc = fmaf(r.z, wres[4 * cq + 2], acc);
            acc = fmaf(r.w, wres[4 * cq + 3], acc);
        }
        xe[(size_t)t * HD + lane] = acc;                     // coalesced
        float t0 = acc * as_, t1 = acc * ad_;
        if (H == 8) {
            #pragma unroll
            for (int m = 1; m < 8; m <<= 1) {
                t0 += __shfl_xor(t0, m, 64);
                t1 += __shfl_xor(t1, m, 64);
            }
            if ((lane & 7) == 0) {
                es[t * 8 + (lane >> 3)] = t0;
                ed[t * 8 + (lane >> 3)] = t1;
            }
        } else {
            #pragma unroll
            for (int m = 1; m < 64; m <<= 1) {
                t0 += __shfl_xor(t0, m, 64);
                t1 += __shfl_xor(t1, m, 64);
            }
            if (lane == 0) { es[t] = t0; ed[t] = t1; }
        }
    }
}

// layer 0: proj fused in. h row computed per-lane, broadcast via LDS row write.
__global__ __launch_bounds__(256, 4)
void fused0_kernel(const float* __restrict__ x, const float* __restrict__ pw,
                   const float* __restrict__ pb, const float* __restrict__ w,
                   const float* __restrict__ asrc, const float* __restrict__ adst,
                   float* __restrict__ xe, float* __restrict__ es, float* __restrict__ ed) {
    __shared__ float tile[GT * HD];
    __shared__ float xt[S * GT];
    int base = blockIdx.x * GT;
    for (int i = threadIdx.x; i < S * GT; i += 256) {
        int s = i >> 6, nl = i & 63;
        int t = base + nl, bb = t / N, n = t - bb * N;
        xt[i] = x[(bb * S + s) * N + n];          // coalesced per s-segment
    }
    int lane = threadIdx.x & 63;
    float wres[HD];
    #pragma unroll
    for (int c = 0; c < HD; ++c) wres[c] = w[c * HD + lane];
    float pwres[S];
    #pragma unroll
    for (int s = 0; s < S; ++s) pwres[s] = pw[s * HD + lane];
    float pbv = pb[lane];
    float as_ = asrc[lane], ad_ = adst[lane];
    __syncthreads();
    int wvid = threadIdx.x >> 6;
    // phase A: this wave's 16 h-rows (lane = channel), written to tile
    for (int j = wvid * 16; j < wvid * 16 + 16; ++j) {
        float hl = pbv;
        #pragma unroll
        for (int s = 0; s < S; ++s)
            hl = fmaf(xt[s * GT + j], pwres[s], hl);         // broadcast read
        tile[j * HD + lane] = hl;                            // own wave's row
    }
    // phase B: gemm + attn (reads only this wave's rows -> no barrier needed)
    for (int j = wvid * 16; j < wvid * 16 + 16; ++j) {
        int t = base + j;
        float acc = 0.f;
        #pragma unroll
        for (int cq = 0; cq < 16; ++cq) {
            float4 r = ((const float4*)tile)[j * 16 + cq];
            acc = fmaf(r.x, wres[4 * cq + 0], acc);
            acc = fmaf(r.y, wres[4 * cq + 1], acc);
            acc = fmaf(r.z, wres[4 * cq + 2], acc);
            acc = fmaf(r.w, wres[4 * cq + 3], acc);
        }
        xe[(size_t)t * HD + lane] = acc;
        float t0 = acc * as_, t1 = acc * ad_;
        #pragma unroll
        for (int m = 1; m < 8; m <<= 1) {
            t0 += __shfl_xor(t0, m, 64);
            t1 += __shfl_xor(t1, m, 64);
        }
        if ((lane & 7) == 0) {
            es[t * 8 + (lane >> 3)] = t0;
            ed[t * 8 + (lane >> 3)] = t1;
        }
    }
}

// ------- fused aggregation: one wave per (batch,node) ------------------------
// 4 groups x 16 lanes; group owns an edge, lane owns 4 channels (float4).
// XCD swizzle: batch bb's blocks land on XCDs {2bb,2bb+1} (round-robin CP
// assumption) so bb's 5.1MB xe slice stays L2-resident. Heuristic only.
template<int H, bool DO_ELU>
__global__ __launch_bounds__(256, 8)
void agg_kernel(const float* __restrict__ xe, const float* __restrict__ es,
                const float* __restrict__ ed, const int* __restrict__ cnt,
                const int* __restrict__ perm, const float* __restrict__ bias,
                float* __restrict__ hout) {
    int g = blockIdx.x;                       // 20000 blocks, multiple of 8
    int bb   = (g & 7) >> 1;                  // batch from XCD pair
    int idx  = (g >> 3) * 2 + (g & 1);        // 0..4999 within batch
    int node = idx * 4 + (threadIdx.x >> 6);  // < 20000
    int lane  = threadIdx.x & 63;
    int group = lane >> 4;
    int c4    = lane & 15;
    int deg = cnt[node];
    int baseE = node * CAP;
    int h = (H == 8) ? (c4 >> 1) : 0;        // channels 4*c4..+3 lie in one head
    const float*  es_b = es + bb * (N * H);
    const float4* xe4  = (const float4*)(xe + bb * (N * HD));
    float edv = ed[(bb * N + node) * H + h];
    float4 acc = {0.f, 0.f, 0.f, 0.f};
    float ssum = 0.f;
    #pragma unroll 2
    for (int jb = 0; jb < deg; jb += 4) {
        int j = jb + group;
        bool valid = (j < deg);
        int src = perm[baseE + (valid ? j : 0)];     // slot 0 always exists
        float e = es_b[src * H + h] + edv;
        e = fmaxf(e, 0.2f * e);                      // leaky_relu(0.2)
        float p = valid ? __expf(e) : 0.f;
        ssum += p;
        float4 xv = xe4[src * 16 + c4];              // 256B/group gather
        acc.x = fmaf(p, xv.x, acc.x);
        acc.y = fmaf(p, xv.y, acc.y);
        acc.z = fmaf(p, xv.z, acc.z);
        acc.w = fmaf(p, xv.w, acc.w);
    }
    #pragma unroll
    for (int m = 16; m < 64; m <<= 1) {
        acc.x += __shfl_xor(acc.x, m, 64);
        acc.y += __shfl_xor(acc.y, m, 64);
        acc.z += __shfl_xor(acc.z, m, 64);
        acc.w += __shfl_xor(acc.w, m, 64);
        ssum  += __shfl_xor(ssum,  m, 64);
    }
    if (lane < 16) {
        float inv = 1.f / ssum;
        const float4* b4 = (const float4*)bias;
        float4 bv = b4[c4];
        float4 r;
        r.x = acc.x * inv + bv.x;
        r.y = acc.y * inv + bv.y;
        r.z = acc.z * inv + bv.z;
        r.w = acc.w * inv + bv.w;
        if (DO_ELU) {
            r.x = (r.x > 0.f) ? r.x : expm1f(r.x);
            r.y = (r.y > 0.f) ? r.y : expm1f(r.y);
            r.z = (r.z > 0.f) ? r.z : expm1f(r.z);
            r.w = (r.w > 0.f) ? r.w : expm1f(r.w);
        }
        ((float4*)hout)[(bb * N + node) * 16 + c4] = r;
    }
}

// ======== conv v5.1: R9's proven no-spill shape, occupancy 2->4 blocks/CU ====
// lane = out-channel o; per dt pass: wres[64] resident, per node j a scalar
// dot accumulated into part[node][lane] in LDS (stride-1 -> conflict-free).
// VGPR=92 fits the 128 cap of LB(256,4); 32.5KB LDS x4 = 130KB <= 160KB.
constexpr int CN = 64;                  // nodes per block (4 waves x 16)
__global__ __launch_bounds__(256, 4)
void conv_out_kernel(const float* __restrict__ h, const float* __restrict__ cwD,
                     const float* __restrict__ cb, const float* __restrict__ ow,
                     const float* __restrict__ ob, float* __restrict__ out) {
    __shared__ float tile[(CN + 2) * HD];        // rows base-1 .. base+CN (16.5KB)
    __shared__ float part[CN * HD];              // per-(node,o) partials (16KB)
    int bb = blockIdx.y;
    int base = blockIdx.x * CN;
    for (int i = threadIdx.x; i < (CN + 2) * (HD / 4); i += 256) {
        int row = i >> 4, q = i & 15;
        int m = base - 1 + row;
        float4 v = {0.f, 0.f, 0.f, 0.f};
        if (m >= 0 && m < N) v = ((const float4*)(h + ((size_t)bb * N + m) * HD))[q];
        ((float4*)tile)[i] = v;
    }
    int lane = threadIdx.x & 63;        // = output channel o
    int wvid = threadIdx.x >> 6;
    float cbv = cb[lane];
    float ow0 = ow[lane * 3 + 0], ow1 = ow[lane * 3 + 1], ow2 = ow[lane * 3 + 2];
    float ob0 = ob[0], ob1 = ob[1], ob2 = ob[2];
    #pragma unroll
    for (int j = 0; j < 16; ++j)                 // init own wave's partials
        part[(wvid * 16 + j) * HD + lane] = cbv;
    __syncthreads();
    #pragma unroll 1
    for (int dt = 0; dt < 3; ++dt) {
        float wres[HD];                          // cwD[dt][c][lane], coalesced
        #pragma unroll
        for (int c = 0; c < HD; ++c) wres[c] = cwD[dt * (HD * HD) + c * HD + lane];
        #pragma unroll 1
        for (int j = 0; j < 16; ++j) {
            const float4* rp = (const float4*)(tile + (wvid * 16 + j + dt) * HD);
            float a = 0.f;
            #pragma unroll
            for (int cq = 0; cq < 16; ++cq) {
                float4 r = rp[cq];               // broadcast read (uniform addr)
                a = fmaf(r.x, wres[4 * cq + 0], a);
                a = fmaf(r.y, wres[4 * cq + 1], a);
                a = fmaf(r.z, wres[4 * cq + 2], a);
                a = fmaf(r.w, wres[4 * cq + 3], a);
            }
            part[(wvid * 16 + j) * HD + lane] += a;   // wave-local LDS RMW
        }
    }
    // epilogue: relu + 64->3 via butterfly
    #pragma unroll 1
    for (int j = 0; j < 16; ++j) {
        float v = fmaxf(part[(wvid * 16 + j) * HD + lane], 0.f);
        float t0 = v * ow0, t1 = v * ow1, t2 = v * ow2;
        #pragma unroll
        for (int m = 1; m < 64; m <<= 1) {
            t0 += __shfl_xor(t0, m, 64);
            t1 += __shfl_xor(t1, m, 64);
            t2 += __shfl_xor(t2, m, 64);
        }
        int n = base + wvid * 16 + j;
        if (lane < 3 && n < N) {
            float r = (lane == 0) ? t0 + ob0 : (lane == 1) ? t1 + ob1 : t2 + ob2;
            out[(size_t)bb * 3 * N + lane * N + n] = r;
        }
    }
}

extern "C" void kernel_launch(void* const* d_in, const int* in_sizes, int n_in,
                              void* d_out, int out_size, void* d_ws, size_t ws_size,
                              hipStream_t stream) {
    const float* x      = (const float*)d_in[0];
    const int*   ei     = (const int*)  d_in[1];
    const float* proj_w = (const float*)d_in[2];
    const float* proj_b = (const float*)d_in[3];
    const float* g_w [3] = {(const float*)d_in[4], (const float*)d_in[8],  (const float*)d_in[12]};
    const float* g_as[3] = {(const float*)d_in[5], (const float*)d_in[9],  (const float*)d_in[13]};
    const float* g_ad[3] = {(const float*)d_in[6], (const float*)d_in[10], (const float*)d_in[14]};
    const float* g_b [3] = {(const float*)d_in[7], (const float*)d_in[11], (const float*)d_in[15]};
    const float* conv_w = (const float*)d_in[16];
    const float* conv_b = (const float*)d_in[17];
    const float* out_w  = (const float*)d_in[18];
    const float* out_b  = (const float*)d_in[19];
    float* out = (float*)d_out;

    // workspace layout (fp32 elements)
    float* bufA = (float*)d_ws;                      // BN*HD
    float* bufX = bufA + (size_t)BN * HD;            // BN*HD
    float* es   = bufX + (size_t)BN * HD;            // BN*8 (max H)
    float* ed   = es   + (size_t)BN * 8;             // BN*8
    int* cnt  = (int*)(ed + (size_t)BN * 8);         // N
    int* perm = cnt + N;                             // N*CAP
    float* cwD = (float*)(perm + (size_t)N * CAP);   // 3*64*64

    const int TB = 256;
    const int gE = (EL + TB - 1) / TB;

    // CSR build: memset + single scatter (padded buckets, no scan)
    hipMemsetAsync(cnt, 0, N * sizeof(int), stream);
    scatter_kernel<<<gE, TB, 0, stream>>>(ei, cnt, perm);

    // conv weight transpose to [dt][c][o]
    tw_kernel<<<(HD * HD * 3 + TB - 1) / TB, TB, 0, stream>>>(conv_w, cwD);

    // layer 0: proj + gemm + attn fused (reads x directly)
    fused0_kernel<<<BN / GT, TB, 0, stream>>>(x, proj_w, proj_b, g_w[0], g_as[0], g_ad[0],
                                              bufX, es, ed);
    agg_kernel<8, true><<<BN / 4, TB, 0, stream>>>(bufX, es, ed, cnt, perm, g_b[0], bufA);

    // layer 1 (H=8) + ELU
    gemm_attn_kernel<8><<<BN / GT, TB, 0, stream>>>(bufA, g_w[1], g_as[1], g_ad[1], bufX, es, ed);
    agg_kernel<8, true><<<BN / 4, TB, 0, stream>>>(bufX, es, ed, cnt, perm, g_b[1], bufA);

    // layer 2 (H=1), no ELU
    gemm_attn_kernel<1><<<BN / GT, TB, 0, stream>>>(bufA, g_w[2], g_as[2], g_ad[2], bufX, es, ed);
    agg_kernel<1, false><<<BN / 4, TB, 0, stream>>>(bufX, es, ed, cnt, perm, g_b[2], bufA);

    // conv1d(k=3) + relu + final projection, writes [B,3,N]
    conv_out_kernel<<<dim3((N + CN - 1) / CN, B), TB, 0, stream>>>(bufA, cwD, conv_b, out_w, out_b, out);
}

// Round 12
// 480.120 us; speedup vs baseline: 4.0247x; 1.5213x over previous
//
#include <hip/hip_runtime.h>
#include <math.h>

constexpr int B  = 4;
constexpr int S  = 12;
constexpr int N  = 20000;
constexpr int HD = 64;
constexpr int E0 = 640000;
constexpr int EL = E0 + N;      // edges + self loops
constexpr int BN = B * N;
constexpr int CAP = 128;        // padded CSR bucket capacity (deg: mean 32, sd 5.7)

// ---------------- padded-bucket CSR build: one kernel, no scan ---------------
__global__ void scatter_kernel(const int* __restrict__ ei, int* __restrict__ cnt,
                               int* __restrict__ perm) {
    int e = blockIdx.x * blockDim.x + threadIdx.x;
    if (e >= EL) return;
    int s, d;
    if (e < E0) { s = ei[e]; d = ei[E0 + e]; }
    else        { s = e - E0; d = s; }
    int pos = atomicAdd(&cnt[d], 1) & (CAP - 1);   // mask: can't corrupt neighbors
    perm[d * CAP + pos] = s;
}

// ---- conv weight transpose: cwD[dt*4096 + c*64 + o] = cw[o*192 + c*3 + dt] --
__global__ void tw_kernel(const float* __restrict__ cw, float* __restrict__ cwD) {
    int i = blockIdx.x * blockDim.x + threadIdx.x;
    if (i >= HD * HD * 3) return;
    int o = i / (HD * 3), rem = i % (HD * 3), c = rem / 3, dt = rem % 3;
    cwD[dt * (HD * HD) + c * HD + o] = cw[i];
}

// ======== gemm family v3: lane = k, weights resident in VGPRs ===============
// wave processes 16 nodes; node rows broadcast from LDS (wave-uniform addr);
// xe stored directly (coalesced 256B per node); es/ed via butterfly shuffle.
constexpr int GT = 64;                  // nodes per block (4 waves x 16)

template<int H>
__global__ __launch_bounds__(256, 4)
void gemm_attn_kernel(const float* __restrict__ hin, const float* __restrict__ w,
                      const float* __restrict__ asrc, const float* __restrict__ adst,
                      float* __restrict__ xe, float* __restrict__ es, float* __restrict__ ed) {
    __shared__ float tile[GT * HD];
    int base = blockIdx.x * GT;
    for (int i = threadIdx.x; i < GT * (HD / 4); i += 256)
        ((float4*)tile)[i] = ((const float4*)(hin + (size_t)base * HD))[i];
    int lane = threadIdx.x & 63;
    float wres[HD];                     // w[c][lane], c compile-time -> VGPRs
    #pragma unroll
    for (int c = 0; c < HD; ++c) wres[c] = w[c * HD + lane];
    float as_ = asrc[lane], ad_ = adst[lane];
    __syncthreads();
    int wvid = threadIdx.x >> 6;
    for (int j = wvid * 16; j < wvid * 16 + 16; ++j) {
        int t = base + j;
        float acc = 0.f;
        #pragma unroll
        for (int cq = 0; cq < 16; ++cq) {
            float4 r = ((const float4*)tile)[j * 16 + cq];   // broadcast read
            acc = fmaf(r.x, wres[4 * cq + 0], acc);
            acc = fmaf(r.y, wres[4 * cq + 1], acc);
            acc = fmaf(r.z, wres[4 * cq + 2], acc);
            acc = fmaf(r.w, wres[4 * cq + 3], acc);
        }
        xe[(size_t)t * HD + lane] = acc;                     // coalesced
        float t0 = acc * as_, t1 = acc * ad_;
        if (H == 8) {
            #pragma unroll
            for (int m = 1; m < 8; m <<= 1) {
                t0 += __shfl_xor(t0, m, 64);
                t1 += __shfl_xor(t1, m, 64);
            }
            if ((lane & 7) == 0) {
                es[t * 8 + (lane >> 3)] = t0;
                ed[t * 8 + (lane >> 3)] = t1;
            }
        } else {
            #pragma unroll
            for (int m = 1; m < 64; m <<= 1) {
                t0 += __shfl_xor(t0, m, 64);
                t1 += __shfl_xor(t1, m, 64);
            }
            if (lane == 0) { es[t] = t0; ed[t] = t1; }
        }
    }
}

// layer 0: proj fused in. h row computed per-lane, broadcast via LDS row write.
__global__ __launch_bounds__(256, 4)
void fused0_kernel(const float* __restrict__ x, const float* __restrict__ pw,
                   const float* __restrict__ pb, const float* __restrict__ w,
                   const float* __restrict__ asrc, const float* __restrict__ adst,
                   float* __restrict__ xe, float* __restrict__ es, float* __restrict__ ed) {
    __shared__ float tile[GT * HD];
    __shared__ float xt[S * GT];
    int base = blockIdx.x * GT;
    for (int i = threadIdx.x; i < S * GT; i += 256) {
        int s = i >> 6, nl = i & 63;
        int t = base + nl, bb = t / N, n = t - bb * N;
        xt[i] = x[(bb * S + s) * N + n];          // coalesced per s-segment
    }
    int lane = threadIdx.x & 63;
    float wres[HD];
    #pragma unroll
    for (int c = 0; c < HD; ++c) wres[c] = w[c * HD + lane];
    float pwres[S];
    #pragma unroll
    for (int s = 0; s < S; ++s) pwres[s] = pw[s * HD + lane];
    float pbv = pb[lane];
    float as_ = asrc[lane], ad_ = adst[lane];
    __syncthreads();
    int wvid = threadIdx.x >> 6;
    // phase A: this wave's 16 h-rows (lane = channel), written to tile
    for (int j = wvid * 16; j < wvid * 16 + 16; ++j) {
        float hl = pbv;
        #pragma unroll
        for (int s = 0; s < S; ++s)
            hl = fmaf(xt[s * GT + j], pwres[s], hl);         // broadcast read
        tile[j * HD + lane] = hl;                            // own wave's row
    }
    // phase B: gemm + attn (reads only this wave's rows -> no barrier needed)
    for (int j = wvid * 16; j < wvid * 16 + 16; ++j) {
        int t = base + j;
        float acc = 0.f;
        #pragma unroll
        for (int cq = 0; cq < 16; ++cq) {
            float4 r = ((const float4*)tile)[j * 16 + cq];
            acc = fmaf(r.x, wres[4 * cq + 0], acc);
            acc = fmaf(r.y, wres[4 * cq + 1], acc);
            acc = fmaf(r.z, wres[4 * cq + 2], acc);
            acc = fmaf(r.w, wres[4 * cq + 3], acc);
        }
        xe[(size_t)t * HD + lane] = acc;
        float t0 = acc * as_, t1 = acc * ad_;
        #pragma unroll
        for (int m = 1; m < 8; m <<= 1) {
            t0 += __shfl_xor(t0, m, 64);
            t1 += __shfl_xor(t1, m, 64);
        }
        if ((lane & 7) == 0) {
            es[t * 8 + (lane >> 3)] = t0;
            ed[t * 8 + (lane >> 3)] = t1;
        }
    }
}

// ------- fused aggregation: one wave per (batch,node) ------------------------
// 4 groups x 16 lanes; group owns an edge, lane owns 4 channels (float4).
// XCD swizzle: batch bb's blocks land on XCDs {2bb,2bb+1} (round-robin CP
// assumption) so bb's 5.1MB xe slice stays L2-resident. Heuristic only.
template<int H, bool DO_ELU>
__global__ __launch_bounds__(256, 8)
void agg_kernel(const float* __restrict__ xe, const float* __restrict__ es,
                const float* __restrict__ ed, const int* __restrict__ cnt,
                const int* __restrict__ perm, const float* __restrict__ bias,
                float* __restrict__ hout) {
    int g = blockIdx.x;                       // 20000 blocks, multiple of 8
    int bb   = (g & 7) >> 1;                  // batch from XCD pair
    int idx  = (g >> 3) * 2 + (g & 1);        // 0..4999 within batch
    int node = idx * 4 + (threadIdx.x >> 6);  // < 20000
    int lane  = threadIdx.x & 63;
    int group = lane >> 4;
    int c4    = lane & 15;
    int deg = cnt[node];
    int baseE = node * CAP;
    int h = (H == 8) ? (c4 >> 1) : 0;        // channels 4*c4..+3 lie in one head
    const float*  es_b = es + bb * (N * H);
    const float4* xe4  = (const float4*)(xe + bb * (N * HD));
    float edv = ed[(bb * N + node) * H + h];
    float4 acc = {0.f, 0.f, 0.f, 0.f};
    float ssum = 0.f;
    #pragma unroll 4
    for (int jb = 0; jb < deg; jb += 4) {
        int j = jb + group;
        bool valid = (j < deg);
        int src = perm[baseE + (valid ? j : 0)];     // slot 0 always exists
        float e = es_b[src * H + h] + edv;
        e = fmaxf(e, 0.2f * e);                      // leaky_relu(0.2)
        float p = valid ? __expf(e) : 0.f;
        ssum += p;
        float4 xv = xe4[src * 16 + c4];              // 256B/group gather
        acc.x = fmaf(p, xv.x, acc.x);
        acc.y = fmaf(p, xv.y, acc.y);
        acc.z = fmaf(p, xv.z, acc.z);
        acc.w = fmaf(p, xv.w, acc.w);
    }
    #pragma unroll
    for (int m = 16; m < 64; m <<= 1) {
        acc.x += __shfl_xor(acc.x, m, 64);
        acc.y += __shfl_xor(acc.y, m, 64);
        acc.z += __shfl_xor(acc.z, m, 64);
        acc.w += __shfl_xor(acc.w, m, 64);
        ssum  += __shfl_xor(ssum,  m, 64);
    }
    if (lane < 16) {
        float inv = 1.f / ssum;
        const float4* b4 = (const float4*)bias;
        float4 bv = b4[c4];
        float4 r;
        r.x = acc.x * inv + bv.x;
        r.y = acc.y * inv + bv.y;
        r.z = acc.z * inv + bv.z;
        r.w = acc.w * inv + bv.w;
        if (DO_ELU) {
            r.x = (r.x > 0.f) ? r.x : expm1f(r.x);
            r.y = (r.y > 0.f) ? r.y : expm1f(r.y);
            r.z = (r.z > 0.f) ? r.z : expm1f(r.z);
            r.w = (r.w > 0.f) ? r.w : expm1f(r.w);
        }
        ((float4*)hout)[(bb * N + node) * 16 + c4] = r;
    }
}

// ======== conv v5 @ LB(256,2): the proven no-spill config (R9, 101us) ========
// lane = out-channel o; per dt pass: wres[64] resident, per node j a scalar
// dot accumulated into part[node][lane] in LDS (stride-1 -> conflict-free).
// VGPR=92, FETCH ~10.5MB. Do NOT raise launch_bounds: LB(256,4) makes the
// allocator cap at 64-128 VGPR and spill wres (R10/R11: 0.5-1.8GB scratch).
constexpr int CN = 64;                  // nodes per block (4 waves x 16)
__global__ __launch_bounds__(256, 2)
void conv_out_kernel(const float* __restrict__ h, const float* __restrict__ cwD,
                     const float* __restrict__ cb, const float* __restrict__ ow,
                     const float* __restrict__ ob, float* __restrict__ out) {
    __shared__ float tile[(CN + 2) * HD];        // rows base-1 .. base+CN (16.5KB)
    __shared__ float part[CN * HD];              // per-(node,o) partials (16KB)
    int bb = blockIdx.y;
    int base = blockIdx.x * CN;
    for (int i = threadIdx.x; i < (CN + 2) * (HD / 4); i += 256) {
        int row = i >> 4, q = i & 15;
        int m = base - 1 + row;
        float4 v = {0.f, 0.f, 0.f, 0.f};
        if (m >= 0 && m < N) v = ((const float4*)(h + ((size_t)bb * N + m) * HD))[q];
        ((float4*)tile)[i] = v;
    }
    int lane = threadIdx.x & 63;        // = output channel o
    int wvid = threadIdx.x >> 6;
    float cbv = cb[lane];
    float ow0 = ow[lane * 3 + 0], ow1 = ow[lane * 3 + 1], ow2 = ow[lane * 3 + 2];
    float ob0 = ob[0], ob1 = ob[1], ob2 = ob[2];
    #pragma unroll
    for (int j = 0; j < 16; ++j)                 // init own wave's partials
        part[(wvid * 16 + j) * HD + lane] = cbv;
    __syncthreads();
    #pragma unroll 1
    for (int dt = 0; dt < 3; ++dt) {
        float wres[HD];                          // cwD[dt][c][lane], coalesced
        #pragma unroll
        for (int c = 0; c < HD; ++c) wres[c] = cwD[dt * (HD * HD) + c * HD + lane];
        #pragma unroll 1
        for (int j = 0; j < 16; ++j) {
            const float4* rp = (const float4*)(tile + (wvid * 16 + j + dt) * HD);
            float a = 0.f;
            #pragma unroll
            for (int cq = 0; cq < 16; ++cq) {
                float4 r = rp[cq];               // broadcast read (uniform addr)
                a = fmaf(r.x, wres[4 * cq + 0], a);
                a = fmaf(r.y, wres[4 * cq + 1], a);
                a = fmaf(r.z, wres[4 * cq + 2], a);
                a = fmaf(r.w, wres[4 * cq + 3], a);
            }
            part[(wvid * 16 + j) * HD + lane] += a;   // wave-local LDS RMW
        }
    }
    // epilogue: relu + 64->3 via butterfly
    #pragma unroll 1
    for (int j = 0; j < 16; ++j) {
        float v = fmaxf(part[(wvid * 16 + j) * HD + lane], 0.f);
        float t0 = v * ow0, t1 = v * ow1, t2 = v * ow2;
        #pragma unroll
        for (int m = 1; m < 64; m <<= 1) {
            t0 += __shfl_xor(t0, m, 64);
            t1 += __shfl_xor(t1, m, 64);
            t2 += __shfl_xor(t2, m, 64);
        }
        int n = base + wvid * 16 + j;
        if (lane < 3 && n < N) {
            float r = (lane == 0) ? t0 + ob0 : (lane == 1) ? t1 + ob1 : t2 + ob2;
            out[(size_t)bb * 3 * N + lane * N + n] = r;
        }
    }
}

extern "C" void kernel_launch(void* const* d_in, const int* in_sizes, int n_in,
                              void* d_out, int out_size, void* d_ws, size_t ws_size,
                              hipStream_t stream) {
    const float* x      = (const float*)d_in[0];
    const int*   ei     = (const int*)  d_in[1];
    const float* proj_w = (const float*)d_in[2];
    const float* proj_b = (const float*)d_in[3];
    const float* g_w [3] = {(const float*)d_in[4], (const float*)d_in[8],  (const float*)d_in[12]};
    const float* g_as[3] = {(const float*)d_in[5], (const float*)d_in[9],  (const float*)d_in[13]};
    const float* g_ad[3] = {(const float*)d_in[6], (const float*)d_in[10], (const float*)d_in[14]};
    const float* g_b [3] = {(const float*)d_in[7], (const float*)d_in[11], (const float*)d_in[15]};
    const float* conv_w = (const float*)d_in[16];
    const float* conv_b = (const float*)d_in[17];
    const float* out_w  = (const float*)d_in[18];
    const float* out_b  = (const float*)d_in[19];
    float* out = (float*)d_out;

    // workspace layout (fp32 elements)
    float* bufA = (float*)d_ws;                      // BN*HD
    float* bufX = bufA + (size_t)BN * HD;            // BN*HD
    float* es   = bufX + (size_t)BN * HD;            // BN*8 (max H)
    float* ed   = es   + (size_t)BN * 8;             // BN*8
    int* cnt  = (int*)(ed + (size_t)BN * 8);         // N
    int* perm = cnt + N;                             // N*CAP
    float* cwD = (float*)(perm + (size_t)N * CAP);   // 3*64*64

    const int TB = 256;
    const int gE = (EL + TB - 1) / TB;

    // CSR build: memset + single scatter (padded buckets, no scan)
    hipMemsetAsync(cnt, 0, N * sizeof(int), stream);
    scatter_kernel<<<gE, TB, 0, stream>>>(ei, cnt, perm);

    // conv weight transpose to [dt][c][o]
    tw_kernel<<<(HD * HD * 3 + TB - 1) / TB, TB, 0, stream>>>(conv_w, cwD);

    // layer 0: proj + gemm + attn fused (reads x directly)
    fused0_kernel<<<BN / GT, TB, 0, stream>>>(x, proj_w, proj_b, g_w[0], g_as[0], g_ad[0],
                                              bufX, es, ed);
    agg_kernel<8, true><<<BN / 4, TB, 0, stream>>>(bufX, es, ed, cnt, perm, g_b[0], bufA);

    // layer 1 (H=8) + ELU
    gemm_attn_kernel<8><<<BN / GT, TB, 0, stream>>>(bufA, g_w[1], g_as[1], g_ad[1], bufX, es, ed);
    agg_kernel<8, true><<<BN / 4, TB, 0, stream>>>(bufX, es, ed, cnt, perm, g_b[1], bufA);

    // layer 2 (H=1), no ELU
    gemm_attn_kernel<1><<<BN / GT, TB, 0, stream>>>(bufA, g_w[2], g_as[2], g_ad[2], bufX, es, ed);
    agg_kernel<1, false><<<BN / 4, TB, 0, stream>>>(bufX, es, ed, cnt, perm, g_b[2], bufA);

    // conv1d(k=3) + relu + final projection, writes [B,3,N]
    conv_out_kernel<<<dim3((N + CN - 1) / CN, B), TB, 0, stream>>>(bufA, cwD, conv_b, out_w, out_b, out);
}

// Round 13
// 447.151 us; speedup vs baseline: 4.3214x; 1.0737x over previous
//
#include <hip/hip_runtime.h>
#include <math.h>

constexpr int B  = 4;
constexpr int S  = 12;
constexpr int N  = 20000;
constexpr int HD = 64;
constexpr int E0 = 640000;
constexpr int EL = E0 + N;      // edges + self loops
constexpr int BN = B * N;
constexpr int CAP = 128;        // padded CSR bucket capacity (deg: mean 32, sd 5.7)

// ---------------- padded-bucket CSR build: one kernel, no scan ---------------
__global__ void scatter_kernel(const int* __restrict__ ei, int* __restrict__ cnt,
                               int* __restrict__ perm) {
    int e = blockIdx.x * blockDim.x + threadIdx.x;
    if (e >= EL) return;
    int s, d;
    if (e < E0) { s = ei[e]; d = ei[E0 + e]; }
    else        { s = e - E0; d = s; }
    int pos = atomicAdd(&cnt[d], 1) & (CAP - 1);   // mask: can't corrupt neighbors
    perm[d * CAP + pos] = s;
}

// ---- conv weight transpose: cwD[dt*4096 + c*64 + o] = cw[o*192 + c*3 + dt] --
__global__ void tw_kernel(const float* __restrict__ cw, float* __restrict__ cwD) {
    int i = blockIdx.x * blockDim.x + threadIdx.x;
    if (i >= HD * HD * 3) return;
    int o = i / (HD * 3), rem = i % (HD * 3), c = rem / 3, dt = rem % 3;
    cwD[dt * (HD * HD) + c * HD + o] = cw[i];
}

// ======== gemm family v3: lane = k, weights resident in VGPRs ===============
// wave processes 16 nodes; node rows broadcast from LDS (wave-uniform addr);
// xe stored directly (coalesced 256B per node); es/ed via butterfly shuffle.
constexpr int GT = 64;                  // nodes per block (4 waves x 16)

template<int H>
__global__ __launch_bounds__(256, 4)
void gemm_attn_kernel(const float* __restrict__ hin, const float* __restrict__ w,
                      const float* __restrict__ asrc, const float* __restrict__ adst,
                      float* __restrict__ xe, float* __restrict__ es, float* __restrict__ ed) {
    __shared__ float tile[GT * HD];
    int base = blockIdx.x * GT;
    for (int i = threadIdx.x; i < GT * (HD / 4); i += 256)
        ((float4*)tile)[i] = ((const float4*)(hin + (size_t)base * HD))[i];
    int lane = threadIdx.x & 63;
    float wres[HD];                     // w[c][lane], c compile-time -> VGPRs
    #pragma unroll
    for (int c = 0; c < HD; ++c) wres[c] = w[c * HD + lane];
    float as_ = asrc[lane], ad_ = adst[lane];
    __syncthreads();
    int wvid = threadIdx.x >> 6;
    for (int j = wvid * 16; j < wvid * 16 + 16; ++j) {
        int t = base + j;
        float acc = 0.f;
        #pragma unroll
        for (int cq = 0; cq < 16; ++cq) {
            float4 r = ((const float4*)tile)[j * 16 + cq];   // broadcast read
            acc = fmaf(r.x, wres[4 * cq + 0], acc);
            acc = fmaf(r.y, wres[4 * cq + 1], acc);
            acc = fmaf(r.z, wres[4 * cq + 2], acc);
            acc = fmaf(r.w, wres[4 * cq + 3], acc);
        }
        xe[(size_t)t * HD + lane] = acc;                     // coalesced
        float t0 = acc * as_, t1 = acc * ad_;
        if (H == 8) {
            #pragma unroll
            for (int m = 1; m < 8; m <<= 1) {
                t0 += __shfl_xor(t0, m, 64);
                t1 += __shfl_xor(t1, m, 64);
            }
            if ((lane & 7) == 0) {
                es[t * 8 + (lane >> 3)] = t0;
                ed[t * 8 + (lane >> 3)] = t1;
            }
        } else {
            #pragma unroll
            for (int m = 1; m < 64; m <<= 1) {
                t0 += __shfl_xor(t0, m, 64);
                t1 += __shfl_xor(t1, m, 64);
            }
            if (lane == 0) { es[t] = t0; ed[t] = t1; }
        }
    }
}

// layer 0: proj fused in. h row computed per-lane, broadcast via LDS row write.
__global__ __launch_bounds__(256, 4)
void fused0_kernel(const float* __restrict__ x, const float* __restrict__ pw,
                   const float* __restrict__ pb, const float* __restrict__ w,
                   const float* __restrict__ asrc, const float* __restrict__ adst,
                   float* __restrict__ xe, float* __restrict__ es, float* __restrict__ ed) {
    __shared__ float tile[GT * HD];
    __shared__ float xt[S * GT];
    int base = blockIdx.x * GT;
    for (int i = threadIdx.x; i < S * GT; i += 256) {
        int s = i >> 6, nl = i & 63;
        int t = base + nl, bb = t / N, n = t - bb * N;
        xt[i] = x[(bb * S + s) * N + n];          // coalesced per s-segment
    }
    int lane = threadIdx.x & 63;
    float wres[HD];
    #pragma unroll
    for (int c = 0; c < HD; ++c) wres[c] = w[c * HD + lane];
    float pwres[S];
    #pragma unroll
    for (int s = 0; s < S; ++s) pwres[s] = pw[s * HD + lane];
    float pbv = pb[lane];
    float as_ = asrc[lane], ad_ = adst[lane];
    __syncthreads();
    int wvid = threadIdx.x >> 6;
    // phase A: this wave's 16 h-rows (lane = channel), written to tile
    for (int j = wvid * 16; j < wvid * 16 + 16; ++j) {
        float hl = pbv;
        #pragma unroll
        for (int s = 0; s < S; ++s)
            hl = fmaf(xt[s * GT + j], pwres[s], hl);         // broadcast read
        tile[j * HD + lane] = hl;                            // own wave's row
    }
    // phase B: gemm + attn (reads only this wave's rows -> no barrier needed)
    for (int j = wvid * 16; j < wvid * 16 + 16; ++j) {
        int t = base + j;
        float acc = 0.f;
        #pragma unroll
        for (int cq = 0; cq < 16; ++cq) {
            float4 r = ((const float4*)tile)[j * 16 + cq];
            acc = fmaf(r.x, wres[4 * cq + 0], acc);
            acc = fmaf(r.y, wres[4 * cq + 1], acc);
            acc = fmaf(r.z, wres[4 * cq + 2], acc);
            acc = fmaf(r.w, wres[4 * cq + 3], acc);
        }
        xe[(size_t)t * HD + lane] = acc;
        float t0 = acc * as_, t1 = acc * ad_;
        #pragma unroll
        for (int m = 1; m < 8; m <<= 1) {
            t0 += __shfl_xor(t0, m, 64);
            t1 += __shfl_xor(t1, m, 64);
        }
        if ((lane & 7) == 0) {
            es[t * 8 + (lane >> 3)] = t0;
            ed[t * 8 + (lane >> 3)] = t1;
        }
    }
}

// ------- fused aggregation: one wave per (batch,node) ------------------------
// 4 groups x 16 lanes; group owns an edge, lane owns 4 channels (float4).
// XCD swizzle: batch bb's blocks land on XCDs {2bb,2bb+1} (round-robin CP
// assumption) so bb's 5.1MB xe slice stays L2-resident. Heuristic only.
template<int H, bool DO_ELU>
__global__ __launch_bounds__(256, 8)
void agg_kernel(const float* __restrict__ xe, const float* __restrict__ es,
                const float* __restrict__ ed, const int* __restrict__ cnt,
                const int* __restrict__ perm, const float* __restrict__ bias,
                float* __restrict__ hout) {
    int g = blockIdx.x;                       // 20000 blocks, multiple of 8
    int bb   = (g & 7) >> 1;                  // batch from XCD pair
    int idx  = (g >> 3) * 2 + (g & 1);        // 0..4999 within batch
    int node = idx * 4 + (threadIdx.x >> 6);  // < 20000
    int lane  = threadIdx.x & 63;
    int group = lane >> 4;
    int c4    = lane & 15;
    int deg = cnt[node];
    int baseE = node * CAP;
    int h = (H == 8) ? (c4 >> 1) : 0;        // channels 4*c4..+3 lie in one head
    const float*  es_b = es + bb * (N * H);
    const float4* xe4  = (const float4*)(xe + bb * (N * HD));
    float edv = ed[(bb * N + node) * H + h];
    float4 acc = {0.f, 0.f, 0.f, 0.f};
    float ssum = 0.f;
    #pragma unroll 4
    for (int jb = 0; jb < deg; jb += 4) {
        int j = jb + group;
        bool valid = (j < deg);
        int src = perm[baseE + (valid ? j : 0)];     // slot 0 always exists
        float e = es_b[src * H + h] + edv;
        e = fmaxf(e, 0.2f * e);                      // leaky_relu(0.2)
        float p = valid ? __expf(e) : 0.f;
        ssum += p;
        float4 xv = xe4[src * 16 + c4];              // 256B/group gather
        acc.x = fmaf(p, xv.x, acc.x);
        acc.y = fmaf(p, xv.y, acc.y);
        acc.z = fmaf(p, xv.z, acc.z);
        acc.w = fmaf(p, xv.w, acc.w);
    }
    #pragma unroll
    for (int m = 16; m < 64; m <<= 1) {
        acc.x += __shfl_xor(acc.x, m, 64);
        acc.y += __shfl_xor(acc.y, m, 64);
        acc.z += __shfl_xor(acc.z, m, 64);
        acc.w += __shfl_xor(acc.w, m, 64);
        ssum  += __shfl_xor(ssum,  m, 64);
    }
    if (lane < 16) {
        float inv = 1.f / ssum;
        const float4* b4 = (const float4*)bias;
        float4 bv = b4[c4];
        float4 r;
        r.x = acc.x * inv + bv.x;
        r.y = acc.y * inv + bv.y;
        r.z = acc.z * inv + bv.z;
        r.w = acc.w * inv + bv.w;
        if (DO_ELU) {
            r.x = (r.x > 0.f) ? r.x : expm1f(r.x);
            r.y = (r.y > 0.f) ? r.y : expm1f(r.y);
            r.z = (r.z > 0.f) ? r.z : expm1f(r.z);
            r.w = (r.w > 0.f) ? r.w : expm1f(r.w);
        }
        ((float4*)hout)[(bb * N + node) * 16 + c4] = r;
    }
}

// ======== conv v7: 1-wave blocks, node rows via SCALAR loads =================
// Block = 64 threads = 1 wave, 16 nodes. Row addresses are built ONLY from
// blockIdx + loop constants -> provably wave-uniform -> s_load (scalar pipe,
// parallel to VALU). Replaces v5's 768 wave-uniform ds_read_b128 broadcasts
// (12cyc/16B, the measured 100us bottleneck). Weights stay in the proven
// wres[64]-resident shape; partials in wave-private LDS (no syncthreads, no
// register-array-across-reload -> no spill). Tripwire: FETCH/WRITE explosion.
constexpr int CVN = 16;                 // nodes per (1-wave) block
__global__ __launch_bounds__(64, 2)
void conv_out_kernel(const float* __restrict__ h, const float* __restrict__ cwD,
                     const float* __restrict__ cb, const float* __restrict__ ow,
                     const float* __restrict__ ob, float* __restrict__ out) {
    __shared__ float part[CVN * HD];    // 4KB, wave-private
    int bb = blockIdx.y;
    int base = blockIdx.x * CVN;        // N = 1250*16 exact
    int lane = threadIdx.x;             // = output channel o
    float cbv = cb[lane];
    float ow0 = ow[lane * 3 + 0], ow1 = ow[lane * 3 + 1], ow2 = ow[lane * 3 + 2];
    float ob0 = ob[0], ob1 = ob[1], ob2 = ob[2];
    #pragma unroll
    for (int j = 0; j < CVN; ++j) part[j * HD + lane] = cbv;
    #pragma unroll 1
    for (int dt = 0; dt < 3; ++dt) {
        float wres[HD];                 // cwD[dt][c][lane], coalesced VMEM
        #pragma unroll
        for (int c = 0; c < HD; ++c) wres[c] = cwD[dt * (HD * HD) + c * HD + lane];
        #pragma unroll 1
        for (int j = 0; j < CVN; ++j) {
            int m = base + j + dt - 1;
            if (m >= 0 && m < N) {      // uniform branch (s_cbranch)
                const float* hp = h + ((size_t)bb * N + m) * HD;   // uniform -> s_load
                float a = 0.f;
                #pragma unroll
                for (int c = 0; c < HD; ++c)
                    a = fmaf(hp[c], wres[c], a);    // v_fma with SGPR operand
                part[j * HD + lane] += a;           // wave-local LDS RMW
            }
        }
    }
    // epilogue: relu + 64->3 via butterfly
    #pragma unroll 1
    for (int j = 0; j < CVN; ++j) {
        float v = fmaxf(part[j * HD + lane], 0.f);
        float t0 = v * ow0, t1 = v * ow1, t2 = v * ow2;
        #pragma unroll
        for (int m = 1; m < 64; m <<= 1) {
            t0 += __shfl_xor(t0, m, 64);
            t1 += __shfl_xor(t1, m, 64);
            t2 += __shfl_xor(t2, m, 64);
        }
        int n = base + j;               // always < N (1250*16 = 20000)
        if (lane < 3) {
            float r = (lane == 0) ? t0 + ob0 : (lane == 1) ? t1 + ob1 : t2 + ob2;
            out[(size_t)bb * 3 * N + lane * N + n] = r;
        }
    }
}

extern "C" void kernel_launch(void* const* d_in, const int* in_sizes, int n_in,
                              void* d_out, int out_size, void* d_ws, size_t ws_size,
                              hipStream_t stream) {
    const float* x      = (const float*)d_in[0];
    const int*   ei     = (const int*)  d_in[1];
    const float* proj_w = (const float*)d_in[2];
    const float* proj_b = (const float*)d_in[3];
    const float* g_w [3] = {(const float*)d_in[4], (const float*)d_in[8],  (const float*)d_in[12]};
    const float* g_as[3] = {(const float*)d_in[5], (const float*)d_in[9],  (const float*)d_in[13]};
    const float* g_ad[3] = {(const float*)d_in[6], (const float*)d_in[10], (const float*)d_in[14]};
    const float* g_b [3] = {(const float*)d_in[7], (const float*)d_in[11], (const float*)d_in[15]};
    const float* conv_w = (const float*)d_in[16];
    const float* conv_b = (const float*)d_in[17];
    const float* out_w  = (const float*)d_in[18];
    const float* out_b  = (const float*)d_in[19];
    float* out = (float*)d_out;

    // workspace layout (fp32 elements)
    float* bufA = (float*)d_ws;                      // BN*HD
    float* bufX = bufA + (size_t)BN * HD;            // BN*HD
    float* es   = bufX + (size_t)BN * HD;            // BN*8 (max H)
    float* ed   = es   + (size_t)BN * 8;             // BN*8
    int* cnt  = (int*)(ed + (size_t)BN * 8);         // N
    int* perm = cnt + N;                             // N*CAP
    float* cwD = (float*)(perm + (size_t)N * CAP);   // 3*64*64

    const int TB = 256;
    const int gE = (EL + TB - 1) / TB;

    // CSR build: memset + single scatter (padded buckets, no scan)
    hipMemsetAsync(cnt, 0, N * sizeof(int), stream);
    scatter_kernel<<<gE, TB, 0, stream>>>(ei, cnt, perm);

    // conv weight transpose to [dt][c][o]
    tw_kernel<<<(HD * HD * 3 + TB - 1) / TB, TB, 0, stream>>>(conv_w, cwD);

    // layer 0: proj + gemm + attn fused (reads x directly)
    fused0_kernel<<<BN / GT, TB, 0, stream>>>(x, proj_w, proj_b, g_w[0], g_as[0], g_ad[0],
                                              bufX, es, ed);
    agg_kernel<8, true><<<BN / 4, TB, 0, stream>>>(bufX, es, ed, cnt, perm, g_b[0], bufA);

    // layer 1 (H=8) + ELU
    gemm_attn_kernel<8><<<BN / GT, TB, 0, stream>>>(bufA, g_w[1], g_as[1], g_ad[1], bufX, es, ed);
    agg_kernel<8, true><<<BN / 4, TB, 0, stream>>>(bufX, es, ed, cnt, perm, g_b[1], bufA);

    // layer 2 (H=1), no ELU
    gemm_attn_kernel<1><<<BN / GT, TB, 0, stream>>>(bufA, g_w[2], g_as[2], g_ad[2], bufX, es, ed);
    agg_kernel<1, false><<<BN / 4, TB, 0, stream>>>(bufX, es, ed, cnt, perm, g_b[2], bufA);

    // conv1d(k=3) + relu + final projection, writes [B,3,N]
    conv_out_kernel<<<dim3(N / CVN, B), 64, 0, stream>>>(bufA, cwD, conv_b, out_w, out_b, out);
}